// Round 1
// baseline (274.583 us; speedup 1.0000x reference)
//
#include <hip/hip_runtime.h>

#define H 32
#define SEQ 512
#define BM 16          // batch rows per block (= MFMA N)
#define NTHREADS 1024  // 16 waves: 8 layer-1 waves + 8 layer-2 waves; 4 waves/SIMD
#define HSTRIDE 40     // halves per h-row: 80B rows, 16B-aligned b128 frags

typedef _Float16 half8 __attribute__((ext_vector_type(8)));
typedef __attribute__((ext_vector_type(4))) float f32x4;

#define L2E 1.44269504088896340736f

__device__ __forceinline__ float rcp_(float x)  { return __builtin_amdgcn_rcpf(x); }
__device__ __forceinline__ float exp2_(float x) { return __builtin_amdgcn_exp2f(x); }  // raw v_exp_f32
#define MFMA16(A, B, C) __builtin_amdgcn_mfma_f32_16x16x32_f16((A), (B), (C), 0, 0, 0)

// LSTM cell: 5 v_exp + 2 v_rcp (identical numerics to the 258us version)
__device__ __forceinline__ float cell(const f32x4& g, float& cst) {
    float ei = exp2_(g[0]), ef = exp2_(g[1]), eg = exp2_(g[2]), eo = exp2_(g[3]);
    float A  = 1.f + ei, F = 1.f + ef;
    float Gp = eg + 1.f, Gm = eg - 1.f;
    float t1 = A * Gp;
    float num = fmaf(cst, t1, Gm * F);
    float cn  = num * rcp_(F * t1);
    cst = cn;
    float ec = exp2_(fminf(cn * (2.f * L2E), 80.f));
    return (ec - 1.f) * rcp_((1.f + eo) * (ec + 1.f));
}

__global__ __launch_bounds__(NTHREADS, 4) void lstm_kernel(
    const float* __restrict__ x,      // [4096,512]
    const float* __restrict__ w_ih0,  // [128,1]
    const float* __restrict__ w_hh0,  // [128,32]
    const float* __restrict__ b_ih0, const float* __restrict__ b_hh0,
    const float* __restrict__ w_ih1,  // [128,32]
    const float* __restrict__ w_hh1,  // [128,32]
    const float* __restrict__ b_ih1, const float* __restrict__ b_hh1,
    const float* __restrict__ fc1_w,  // [16,32]
    const float* __restrict__ fc1_b,  // [16]
    const float* __restrict__ fc2_w,  // [1,16]
    const float* __restrict__ fc2_b,  // [1]
    float* __restrict__ out)          // [4096]
{
    __shared__ __align__(16) float    xbufT[SEQ * BM];            // 32 KB, [step][row]
    __shared__ __align__(16) _Float16 h1s[4][BM * HSTRIDE];       // 4-deep h1 ring (fp16)
    __shared__ __align__(16) _Float16 h2s[2][BM * HSTRIDE];       // ping-pong h2 (fp16)
    __shared__ __align__(16) float    h2f[BM * 33];
    __shared__ __align__(16) float    yb[BM * 17];

    const int tid  = threadIdx.x;
    const int lane = tid & 63;
    const int wv   = tid >> 6;          // wave id 0..15
    const int role = wv >> 3;           // 0 = layer-1 wave, 1 = layer-2 wave
    const int w    = wv & 7;            // role-local wave id 0..7
    const int c    = lane & 15;         // frag free-index / batch col
    const int q    = lane >> 4;         // k-quad / D row-group
    const int r0   = blockIdx.x * BM;

    // ---- stage x transposed: xbufT[s][row] ----
    {
        const int row = tid >> 6;           // 0..15
        const int s0  = (tid & 63) * 8;     // 8 steps per thread
        const float* xr = x + (size_t)(r0 + row) * SEQ + s0;
        #pragma unroll
        for (int i = 0; i < 8; i += 4) {
            float4 v = *(const float4*)&xr[i];
            xbufT[(s0 + i + 0) * BM + row] = v.x;
            xbufT[(s0 + i + 1) * BM + row] = v.y;
            xbufT[(s0 + i + 2) * BM + row] = v.z;
            xbufT[(s0 + i + 3) * BM + row] = v.w;
        }
    }
    for (int i = tid; i < 4 * BM * HSTRIDE; i += NTHREADS) ((_Float16*)h1s)[i] = (_Float16)0.f;
    for (int i = tid; i < 2 * BM * HSTRIDE; i += NTHREADS) ((_Float16*)h2s)[i] = (_Float16)0.f;

    // ---- W fragments (A-operand), rows permuted r -> (gate r&3, unit 4w + r>>2)
    // gate scales folded (i,f,o: -L2E ; g: +2L2E) so the cell uses raw v_exp_f32.
    const float gsc[4] = { -L2E, -L2E, 2.f * L2E, -L2E };
    const int worig = (c & 3) * H + 4 * w + (c >> 2);
    const float wsc = gsc[c & 3];
    const int kb = 8 * q;
    const int m = c;                    // batch row owned by this lane
    const int u = 4 * w + q;            // unit owned by this lane

    half8 wa = {}, wb = {};             // role 0: wa=w_hh0 ; role 1: wa=w_ih1, wb=w_hh1
    f32x4 biasv;
    float wx0 = 0.f, wx1 = 0.f, wx2 = 0.f, wx3 = 0.f;
    if (role == 0) {
        const float* p = &w_hh0[worig * H + kb];
        #pragma unroll
        for (int j = 0; j < 8; ++j) wa[j] = (_Float16)(p[j] * wsc);
        #pragma unroll
        for (int g = 0; g < 4; ++g) biasv[g] = (b_ih0[g * H + u] + b_hh0[g * H + u]) * gsc[g];
        wx0 = w_ih0[0 * H + u] * gsc[0];
        wx1 = w_ih0[1 * H + u] * gsc[1];
        wx2 = w_ih0[2 * H + u] * gsc[2];
        wx3 = w_ih0[3 * H + u] * gsc[3];
    } else {
        const float* p = &w_ih1[worig * H + kb];
        #pragma unroll
        for (int j = 0; j < 8; ++j) wa[j] = (_Float16)(p[j] * wsc);
        p = &w_hh1[worig * H + kb];
        #pragma unroll
        for (int j = 0; j < 8; ++j) wb[j] = (_Float16)(p[j] * wsc);
        #pragma unroll
        for (int g = 0; g < 4; ++g) biasv[g] = (b_ih1[g * H + u] + b_hh1[g * H + u]) * gsc[g];
    }

    float cst = 0.f;      // c-state of this lane's cell (c1 for role 0, c2 for role 1)
    float hlast = 0.f;    // role 1: h2(511)

    const int fofs  = c * HSTRIDE + kb;   // b128 frag read offset (halves)
    const int whofs = m * HSTRIDE + u;    // h write offset (halves)

    __syncthreads();

    // Iteration t: L1 waves compute step t (t<512); L2 waves compute step tau=t-2
    // (2 <= t < 514). h1 ring depth 4: write slot t&3, L1 reads (t-1)&3, L2 reads
    // (t-2)&3 -- no collision. h2 ping-pong: write tau&1, read (tau-1)&1.
    // tb is a multiple of 4 so all ring slots are compile-time (= p).
    for (int tb = 0; tb < 516; tb += 4) {
        #pragma unroll
        for (int p = 0; p < 4; ++p) {
            const int t = tb + p;
            if (role == 0) {
                if (t < 512) {
                    half8 a1 = *(const half8*)(&h1s[(p + 3) & 3][0] + fofs);   // h1(t-1)
                    float xv = xbufT[t * BM + m];
                    f32x4 g1 = MFMA16(wa, a1, biasv);
                    g1[0] = fmaf(xv, wx0, g1[0]);
                    g1[1] = fmaf(xv, wx1, g1[1]);
                    g1[2] = fmaf(xv, wx2, g1[2]);
                    g1[3] = fmaf(xv, wx3, g1[3]);
                    float hv = cell(g1, cst);
                    h1s[p][whofs] = (_Float16)hv;                              // h1(t)
                }
            } else {
                if (t >= 2 && t < 514) {
                    half8 a1L = *(const half8*)(&h1s[(p + 2) & 3][0] + fofs);  // h1(t-2)
                    half8 a2  = *(const half8*)(&h2s[(p + 1) & 1][0] + fofs);  // h2(t-3)
                    f32x4 g2 = MFMA16(wb, a2, MFMA16(wa, a1L, biasv));
                    float hv = cell(g2, cst);
                    hlast = hv;
                    h2s[p & 1][whofs] = (_Float16)hv;                          // h2(t-2)
                }
            }
            __syncthreads();
        }
    }

    // ---- FC head ----
    if (role == 1) h2f[m * 33 + u] = hlast;
    __syncthreads();
    if (tid < BM * 16) {
        int rr = tid >> 4, j = tid & 15;
        float acc = fc1_b[j];
        #pragma unroll
        for (int k = 0; k < H; ++k) acc += fc1_w[j * H + k] * h2f[rr * 33 + k];
        acc = acc >= 0.f ? acc : 0.2f * acc;
        yb[rr * 17 + j] = acc * fc2_w[j];
    }
    __syncthreads();
    if (tid < BM) {
        float acc = fc2_b[0];
        #pragma unroll
        for (int j = 0; j < 16; ++j) acc += yb[tid * 17 + j];
        out[r0 + tid] = acc;
    }
}

extern "C" void kernel_launch(void* const* d_in, const int* in_sizes, int n_in,
                              void* d_out, int out_size, void* d_ws, size_t ws_size,
                              hipStream_t stream) {
    const float* x     = (const float*)d_in[0];
    const float* w_ih0 = (const float*)d_in[1];
    const float* w_hh0 = (const float*)d_in[2];
    const float* b_ih0 = (const float*)d_in[3];
    const float* b_hh0 = (const float*)d_in[4];
    const float* w_ih1 = (const float*)d_in[5];
    const float* w_hh1 = (const float*)d_in[6];
    const float* b_ih1 = (const float*)d_in[7];
    const float* b_hh1 = (const float*)d_in[8];
    const float* fc1_w = (const float*)d_in[9];
    const float* fc1_b = (const float*)d_in[10];
    const float* fc2_w = (const float*)d_in[11];
    const float* fc2_b = (const float*)d_in[12];
    float* out = (float*)d_out;

    const int B = in_sizes[0] / SEQ;   // 4096
    hipLaunchKernelGGL(lstm_kernel, dim3(B / BM), dim3(NTHREADS), 0, stream,
                       x, w_ih0, w_hh0, b_ih0, b_hh0, w_ih1, w_hh1, b_ih1, b_hh1,
                       fc1_w, fc1_b, fc2_w, fc2_b, out);
}